// Round 1
// baseline (353.373 us; speedup 1.0000x reference)
//
#include <hip/hip_runtime.h>

// BCEWithLogitsLoss with implicit binary-threshold targets:
//   loss = mean_{i,j}( softplus(x[i,j]) - x[i,j] * (j < targets[i]) )
// Memory-bound single-pass reduction. 256 MiB fp32 read -> ~43 us HBM floor.

__global__ __launch_bounds__(256) void bce_reduce_kernel(
    const float4* __restrict__ in,
    const int*    __restrict__ tgt,
    float*        __restrict__ out,
    int nvec,          // total float4 count (64M / 4)
    int row_shift,     // log2(N/4)
    int row_mask,      // (N/4) - 1
    float inv_count)   // 1 / (B*N)
{
    float acc = 0.f;
    const int stride = gridDim.x * blockDim.x;
    for (int v = blockIdx.x * blockDim.x + threadIdx.x; v < nvec; v += stride) {
        float4 x = in[v];
        int row = v >> row_shift;
        int col = (v & row_mask) << 2;
        int t   = tgt[row];
        // stable softplus: max(x,0) + log(1 + exp(-|x|))
        float s;
        s  = fmaxf(x.x, 0.f) + __logf(1.f + __expf(-fabsf(x.x))) - ((col + 0) < t ? x.x : 0.f);
        s += fmaxf(x.y, 0.f) + __logf(1.f + __expf(-fabsf(x.y))) - ((col + 1) < t ? x.y : 0.f);
        s += fmaxf(x.z, 0.f) + __logf(1.f + __expf(-fabsf(x.z))) - ((col + 2) < t ? x.z : 0.f);
        s += fmaxf(x.w, 0.f) + __logf(1.f + __expf(-fabsf(x.w))) - ((col + 3) < t ? x.w : 0.f);
        acc += s;
    }

    // wave64 shuffle reduction
    #pragma unroll
    for (int off = 32; off > 0; off >>= 1)
        acc += __shfl_down(acc, off, 64);

    __shared__ float wave_sums[4];
    const int lane = threadIdx.x & 63;
    const int wave = threadIdx.x >> 6;
    if (lane == 0) wave_sums[wave] = acc;
    __syncthreads();
    if (threadIdx.x == 0) {
        float b = wave_sums[0] + wave_sums[1] + wave_sums[2] + wave_sums[3];
        atomicAdd(out, b * inv_count);
    }
}

extern "C" void kernel_launch(void* const* d_in, const int* in_sizes, int n_in,
                              void* d_out, int out_size, void* d_ws, size_t ws_size,
                              hipStream_t stream) {
    const float* in  = (const float*)d_in[0];
    const int*   tgt = (const int*)d_in[1];
    float*       out = (float*)d_out;

    const long long total = (long long)in_sizes[0];   // B*N = 67108864
    const int B = in_sizes[1];                        // 8192
    const int N = (int)(total / B);                   // 8192
    const int nvec = (int)(total / 4);
    const int nvec_per_row = N / 4;                   // 2048 (pow2)
    const int row_shift = __builtin_ctz(nvec_per_row);
    const int row_mask  = nvec_per_row - 1;
    const float inv_count = 1.0f / (float)total;

    // d_out is poisoned to 0xAA before every launch; zero it for the atomic.
    hipMemsetAsync(d_out, 0, sizeof(float), stream);

    const int block = 256;
    const int grid  = 2048;   // 8 blocks/CU on 256 CUs; 32 float4/thread
    bce_reduce_kernel<<<grid, block, 0, stream>>>(
        (const float4*)in, tgt, out, nvec, row_shift, row_mask, inv_count);
}